// Round 10
// baseline (34.382 us; speedup 1.0000x reference)
//
#include <hip/hip_runtime.h>
#include <hip/hip_bf16.h>

typedef __attribute__((ext_vector_type(8))) short bf16x8;
typedef __attribute__((ext_vector_type(4))) float f32x4;
typedef unsigned short u16;

static __device__ __forceinline__ u16 f2bf(float f) {
  unsigned u = __builtin_bit_cast(unsigned, f);
  return (u16)((u + 0x7fffu + ((u >> 16) & 1u)) >> 16);
}

// ================= K1: weights -> Apre/Bmat, x -> bf16 (round-9 body, unchanged) ======
__global__ __launch_bounds__(256) void trl_w(
    const float* __restrict__ W0, const float* __restrict__ W1,
    const float* __restrict__ W2, const float* __restrict__ W3,
    const float* __restrict__ W4, const float* __restrict__ W5,
    const float* __restrict__ W6, const float* __restrict__ W7,
    const float* __restrict__ x,
    u16* __restrict__ Apre, u16* __restrict__ Bmat, u16* __restrict__ xb) {
  __shared__ float S1[512];
  __shared__ float S2[4096];
  const int tid = threadIdx.x;
  const int b = blockIdx.x;
  if (b >= 128) {
    const int base4 = (b - 128) * 256 + tid;
#pragma unroll
    for (int q = 0; q < 16; ++q) {
      const int c = base4 + 16384 * q;
      const float4 v = reinterpret_cast<const float4*>(x)[c];
      ushort4 o4;
      o4.x = f2bf(v.x); o4.y = f2bf(v.y); o4.z = f2bf(v.z); o4.w = f2bf(v.w);
      reinterpret_cast<ushort4*>(xb)[c] = o4;
    }
    return;
  }
  if (b < 64) {
    const int r1 = b >> 2;
    const int j3base = (b & 3) << 2;
#pragma unroll
    for (int e0 = 0; e0 < 512; e0 += 256) {
      const int e = e0 + tid;
      const int i0 = e & 3, i1 = (e >> 2) & 7, j1 = e >> 5;
      float s = 0.f;
#pragma unroll
      for (int r0 = 0; r0 < 16; ++r0)
        s += W1[j1 * 128 + i1 * 16 + r0] * W0[(r0 * 16 + r1) * 4 + i0];
      S1[e] = s;  // [j1*32 + i1*4 + i0]
    }
#pragma unroll
    for (int e0 = 0; e0 < 2048; e0 += 256) {
      const int e = e0 + tid;
      const int i3 = e & 3, pd = (e >> 2) & 3, j1 = (e >> 4) & 15, i2 = e >> 8;
      float s = 0.f;
#pragma unroll
      for (int j2 = 0; j2 < 16; ++j2)
        s += W3[(j3base + pd) * 64 + i3 * 16 + j2] * W2[j2 * 128 + i2 * 16 + j1];
      S2[e] = s;  // [i2*256 + j1*16 + pd*4 + i3]
    }
    __syncthreads();
    const int i0 = tid & 3, i1 = (tid >> 2) & 7, i2 = tid >> 5;
#pragma unroll
    for (int pd = 0; pd < 4; ++pd) {
      float a0 = 0.f, a1 = 0.f, a2 = 0.f, a3 = 0.f;
#pragma unroll
      for (int j1 = 0; j1 < 16; ++j1) {
        const float t = S1[j1 * 32 + i1 * 4 + i0];
        const float4 v = *(const float4*)&S2[i2 * 256 + j1 * 16 + pd * 4];
        a0 += t * v.x; a1 += t * v.y; a2 += t * v.z; a3 += t * v.w;
      }
      ushort4 o4;
      o4.x = f2bf(a0); o4.y = f2bf(a1); o4.z = f2bf(a2); o4.w = f2bf(a3);
      *(ushort4*)&Apre[(size_t)(4 * b + pd) * 1024 + i0 * 256 + i1 * 32 + i2 * 4] = o4;
    }
  } else {
    const int c = b - 64;
    const int kh = c >> 4, j5h = (c >> 1) & 7, j6hbase = (c & 1) << 2;
    {
      const int j5l = tid >> 4, j3 = tid & 15;
      float s = 0.f;
#pragma unroll
      for (int kl = 0; kl < 16; ++kl)
        s += W5[(j5h * 16 + j5l) * 16 + kl] * W4[(kh * 16 + kl) * 16 + j3];
      S1[tid] = s;  // [j5l*16 + j3]
    }
#pragma unroll
    for (int e0 = 0; e0 < 4096; e0 += 256) {
      const int e = e0 + tid;
      const int j5l = e & 15, j6hd = (e >> 4) & 3, r1 = (e >> 6) & 15, m7 = e >> 10;
      float s = 0.f;
#pragma unroll
      for (int d = 0; d < 16; ++d)
        s += W7[m7 * 256 + r1 * 16 + d] * W6[((j6hbase + j6hd) * 16 + d) * 16 + j5l];
      S2[e] = s;  // [((m7*16+r1)*4 + j6hd)*16 + j5l]
    }
    __syncthreads();
    const int r1 = (tid >> 2) & 15, j3q = tid & 3;
#pragma unroll
    for (int qq = 0; qq < 4; ++qq) {
      const int od = qq * 4 + (tid >> 6);
      const int m7 = od & 3, j6hd = od >> 2;
      float a0 = 0.f, a1 = 0.f, a2 = 0.f, a3 = 0.f;
#pragma unroll
      for (int j5l = 0; j5l < 16; ++j5l) {
        const float w = S2[((m7 * 16 + r1) * 4 + j6hd) * 16 + j5l];
        const float4 u = *(const float4*)&S1[j5l * 16 + j3q * 4];
        a0 += w * u.x; a1 += w * u.y; a2 += w * u.z; a3 += w * u.w;
      }
      ushort4 o4;
      o4.x = f2bf(a0); o4.y = f2bf(a1); o4.z = f2bf(a2); o4.w = f2bf(a3);
      *(ushort4*)&Bmat[(size_t)(16 * c + od) * 256 + r1 * 16 + j3q * 4] = o4;
    }
  }
}

// ============ K2: Cb(1024x256 bf16) = xb @ Apre^T — EXACT round-2 body & grid =========
// grid dim3(8,32): n0 = bx*32, m0 = by*32. NO swizzle (round-9's swizzle regressed).
__global__ __launch_bounds__(256) void trl_g1(const u16* __restrict__ xb,
                                              const u16* __restrict__ Apre,
                                              u16* __restrict__ Cb) {
  __shared__ float red[3][32 * 33];
  const int tid = threadIdx.x;
  const int wave = tid >> 6, lane = tid & 63;
  const int l15 = lane & 15, l4 = lane >> 4;
  const int m0 = blockIdx.y * 32, n0 = blockIdx.x * 32;
  const int kbase = wave * 256;

  f32x4 acc[2][2] = {};
#pragma unroll
  for (int ks = 0; ks < 8; ++ks) {
    const int k = kbase + ks * 32 + l4 * 8;
    const bf16x8 a0 = *(const bf16x8*)&xb[(size_t)(m0 + l15) * 1024 + k];
    const bf16x8 a1 = *(const bf16x8*)&xb[(size_t)(m0 + 16 + l15) * 1024 + k];
    const bf16x8 b0 = *(const bf16x8*)&Apre[(size_t)(n0 + l15) * 1024 + k];
    const bf16x8 b1 = *(const bf16x8*)&Apre[(size_t)(n0 + 16 + l15) * 1024 + k];
    acc[0][0] = __builtin_amdgcn_mfma_f32_16x16x32_bf16(a0, b0, acc[0][0], 0, 0, 0);
    acc[0][1] = __builtin_amdgcn_mfma_f32_16x16x32_bf16(a0, b1, acc[0][1], 0, 0, 0);
    acc[1][0] = __builtin_amdgcn_mfma_f32_16x16x32_bf16(a1, b0, acc[1][0], 0, 0, 0);
    acc[1][1] = __builtin_amdgcn_mfma_f32_16x16x32_bf16(a1, b1, acc[1][1], 0, 0, 0);
  }
  if (wave > 0) {
#pragma unroll
    for (int fm = 0; fm < 2; ++fm)
#pragma unroll
      for (int fn = 0; fn < 2; ++fn)
#pragma unroll
        for (int r = 0; r < 4; ++r)
          red[wave - 1][(fm * 16 + l4 * 4 + r) * 33 + fn * 16 + l15] = acc[fm][fn][r];
  }
  __syncthreads();
  if (wave == 0) {
#pragma unroll
    for (int fm = 0; fm < 2; ++fm)
#pragma unroll
      for (int fn = 0; fn < 2; ++fn)
#pragma unroll
        for (int r = 0; r < 4; ++r) {
          const int row = fm * 16 + l4 * 4 + r, col = fn * 16 + l15;
          float s = acc[fm][fn][r] + red[0][row * 33 + col] + red[1][row * 33 + col] +
                    red[2][row * 33 + col];
          Cb[(size_t)(m0 + row) * 256 + n0 + col] = f2bf(s);
        }
  }
}

// ============ K3: out = Cb @ Bmat^T + bias — EXACT round-2 body & grid ================
// 256 linear blocks x 4 waves, tile = bid*4+wave. NO swizzle.
__global__ __launch_bounds__(256) void trl_g2(const u16* __restrict__ Cb,
                                              const u16* __restrict__ Bmat,
                                              const float* __restrict__ bias,
                                              float* __restrict__ out) {
  const int tid = threadIdx.x;
  const int wave = tid >> 6, lane = tid & 63;
  const int l15 = lane & 15, l4 = lane >> 4;
  const int tile = blockIdx.x * 4 + wave;
  const int m0 = (tile >> 5) * 32, n0 = (tile & 31) * 32;

  f32x4 acc[2][2] = {};
#pragma unroll
  for (int ks = 0; ks < 8; ++ks) {
    const int k = ks * 32 + l4 * 8;
    const bf16x8 a0 = *(const bf16x8*)&Cb[(size_t)(m0 + l15) * 256 + k];
    const bf16x8 a1 = *(const bf16x8*)&Cb[(size_t)(m0 + 16 + l15) * 256 + k];
    const bf16x8 b0 = *(const bf16x8*)&Bmat[(size_t)(n0 + l15) * 256 + k];
    const bf16x8 b1 = *(const bf16x8*)&Bmat[(size_t)(n0 + 16 + l15) * 256 + k];
    acc[0][0] = __builtin_amdgcn_mfma_f32_16x16x32_bf16(a0, b0, acc[0][0], 0, 0, 0);
    acc[0][1] = __builtin_amdgcn_mfma_f32_16x16x32_bf16(a0, b1, acc[0][1], 0, 0, 0);
    acc[1][0] = __builtin_amdgcn_mfma_f32_16x16x32_bf16(a1, b0, acc[1][0], 0, 0, 0);
    acc[1][1] = __builtin_amdgcn_mfma_f32_16x16x32_bf16(a1, b1, acc[1][1], 0, 0, 0);
  }
#pragma unroll
  for (int fn = 0; fn < 2; ++fn) {
    const int gc = n0 + fn * 16 + l15;
    const float bv = bias[gc];
#pragma unroll
    for (int fm = 0; fm < 2; ++fm)
#pragma unroll
      for (int r = 0; r < 4; ++r) {
        const int gr = m0 + fm * 16 + l4 * 4 + r;
        out[(size_t)gr * 1024 + gc] = acc[fm][fn][r] + bv;
      }
  }
}

extern "C" void kernel_launch(void* const* d_in, const int* in_sizes, int n_in,
                              void* d_out, int out_size, void* d_ws, size_t ws_size,
                              hipStream_t stream) {
  const float* x  = (const float*)d_in[0];
  const float* W0 = (const float*)d_in[1];
  const float* W1 = (const float*)d_in[2];
  const float* W2 = (const float*)d_in[3];
  const float* W3 = (const float*)d_in[4];
  const float* W4 = (const float*)d_in[5];
  const float* W5 = (const float*)d_in[6];
  const float* W6 = (const float*)d_in[7];
  const float* W7 = (const float*)d_in[8];
  const float* bias = (const float*)d_in[9];

  char* ws = (char*)d_ws;
  u16* Apre = (u16*)(ws);                   // 512 KB (256x1024 bf16)
  u16* Bmat = (u16*)(ws + (512 << 10));     // 512 KB (1024x256 bf16)
  u16* xb   = (u16*)(ws + (1024 << 10));    // 2 MB   (1024x1024 bf16)
  u16* Cb   = (u16*)(ws + (3072 << 10));    // 512 KB (1024x256 bf16)
  float* outp = (float*)d_out;

  trl_w<<<192, 256, 0, stream>>>(W0, W1, W2, W3, W4, W5, W6, W7, x, Apre, Bmat, xb);
  trl_g1<<<dim3(8, 32), 256, 0, stream>>>(xb, Apre, Cb);
  trl_g2<<<256, 256, 0, stream>>>(Cb, Bmat, bias, outp);
}